// Round 8
// baseline (325.894 us; speedup 1.0000x reference)
//
#include <hip/hip_runtime.h>

// CRF forward: B=512, T=1024, N=64. fwd/bwd split, one wave per chain.
// Round 8 changes vs round 7:
//  - E pinned in VGPRs via inline-asm barrier. R3-R7 consistently show
//    (VGPR_Count frozen at 88) that the allocator reloads E from LDS every
//    step (invariant-load remat) -> 32 ds_read_b128/step instead of 16.
//    asm-defined values cannot be reloaded: allocator must keep them.
//  - Base-2 log domain: carry alpha*log2e, raw v_exp_f32/v_log_f32
//    (exp2/log2), u premultiplied by log2e in the (off-chain) prefetch.
//    Removes 2 dependent v_mul from the per-step critical path.

typedef float f4 __attribute__((ext_vector_type(4)));

constexpr int Tt = 1024;
constexpr int Nn = 64;
constexpr int ES = 68;  // f32 row stride: 272 B, 16B-aligned, non-pow2
constexpr float LOG2E = 1.44269504088896340736f;
constexpr float LN2   = 0.69314718055994530942f;

__global__ __launch_bounds__(128, 1) void crf_fwd(
    const float* __restrict__ unary,
    const int*   __restrict__ lengths,
    const float* __restrict__ trans,
    float*       __restrict__ out)
{
    const int b    = blockIdx.x;
    const int tid  = threadIdx.x;
    const int w    = tid >> 6;   // 0 = forward wave, 1 = backward wave
    const int lane = tid & 63;

    __shared__ float Ecol[Nn * ES];   // Ecol[j*ES+i] = exp(trans[i][j])
    __shared__ float Erow[Nn * ES];   // Erow[i*ES+j] = exp(trans[i][j])
    __shared__ f4    shp4[2][Nn / 4]; // per-wave p broadcast (16B-aligned)
    __shared__ float shb[Nn];         // beta at midpoint (combine)

    // One-time staging of E = exp(trans), both orientations.
    #pragma unroll
    for (int c = 0; c < (Nn * Nn) / 128; ++c) {
        int idx = c * 128 + tid;
        int i = idx >> 6, j = idx & 63;
        float e = __expf(trans[idx]);
        Erow[i * ES + j] = e;
        Ecol[j * ES + i] = e;
    }
    __syncthreads();

    // Lane's 64 E values (fwd: column `lane`; bwd: row `lane`).
    const f4* eb = (const f4*)((w == 0) ? &Ecol[lane * ES] : &Erow[lane * ES]);
    f4 E0  = eb[0],  E1  = eb[1],  E2  = eb[2],  E3  = eb[3];
    f4 E4  = eb[4],  E5  = eb[5],  E6  = eb[6],  E7  = eb[7];
    f4 E8  = eb[8],  E9  = eb[9],  E10 = eb[10], E11 = eb[11];
    f4 E12 = eb[12], E13 = eb[13], E14 = eb[14], E15 = eb[15];
    // Optimization barrier: values become asm-defined -> not reloadable,
    // not rematerializable. Allocator must keep them in VGPRs.
    asm volatile("" : "+v"(E0), "+v"(E1), "+v"(E2),  "+v"(E3),
                      "+v"(E4), "+v"(E5), "+v"(E6),  "+v"(E7),
                      "+v"(E8), "+v"(E9), "+v"(E10), "+v"(E11),
                      "+v"(E12), "+v"(E13), "+v"(E14), "+v"(E15));

    int L = lengths[b];
    L = L < 1 ? 1 : (L > Tt ? Tt : L);
    const int m = (L - 1) >> 1;

    const float* ub = unary + (size_t)b * Tt * Nn;

    const int trips = (w == 0) ? m : (L - 1 - m);
    const int tbase = (w == 0) ? 1 : (L - 1);
    const int dir   = (w == 0) ? 1 : -1;

    // State in base-2 domain: acc = alpha * log2e (or beta * log2e).
    float acc = (w == 0) ? ub[lane] * LOG2E : 0.0f;
    float* myp = (float*)shp4[w];
    const f4* pp = shp4[w];

    // 4-deep u prefetch, premultiplied by log2e (off the dependent chain).
    float u_cur[4];
    {
        int smax = trips > 0 ? trips - 1 : 0;
        #pragma unroll
        for (int k = 0; k < 4; ++k) {
            int sc = k < smax ? k : smax;
            u_cur[k] = ub[(tbase + dir * sc) * Nn + lane] * LOG2E;
        }
    }

    for (int s0 = 0; s0 < trips; s0 += 4) {
        float u_nxt[4];
        #pragma unroll
        for (int k = 0; k < 4; ++k) {
            int sc = s0 + 4 + k;
            if (sc > trips - 1) sc = trips - 1;
            u_nxt[k] = ub[(tbase + dir * sc) * Nn + lane] * LOG2E;
        }

        #pragma unroll
        for (int k = 0; k < 4; ++k) {
            if (s0 + k >= trips) break;  // wave-uniform

            // fwd: p = exp2(acc - s), update = s + u + log2 z
            // bwd: p = exp2(acc + u - s), update = s + log2 z
            float ui = (w != 0) ? u_cur[k] : 0.0f;
            float uo = (w == 0) ? u_cur[k] : 0.0f;

            float tmpv = acc + ui;
            float sf = __uint_as_float(
                (unsigned)__builtin_amdgcn_readfirstlane((int)__float_as_uint(tmpv)));
            float p = __builtin_amdgcn_exp2f(tmpv - sf);

            myp[lane] = p;  // intra-wave ds_write; LDS pipe in-order

            f4 A0 = {0.f, 0.f, 0.f, 0.f};
            f4 A1 = {0.f, 0.f, 0.f, 0.f};
            f4 A2 = {0.f, 0.f, 0.f, 0.f};
            f4 A3 = {0.f, 0.f, 0.f, 0.f};
            A0 = pp[0]  * E0  + A0;  A1 = pp[1]  * E1  + A1;
            A2 = pp[2]  * E2  + A2;  A3 = pp[3]  * E3  + A3;
            A0 = pp[4]  * E4  + A0;  A1 = pp[5]  * E5  + A1;
            A2 = pp[6]  * E6  + A2;  A3 = pp[7]  * E7  + A3;
            A0 = pp[8]  * E8  + A0;  A1 = pp[9]  * E9  + A1;
            A2 = pp[10] * E10 + A2;  A3 = pp[11] * E11 + A3;
            A0 = pp[12] * E12 + A0;  A1 = pp[13] * E13 + A1;
            A2 = pp[14] * E14 + A2;  A3 = pp[15] * E15 + A3;
            f4 S = (A0 + A1) + (A2 + A3);
            float z = (S.x + S.y) + (S.z + S.w);

            acc = sf + uo + __builtin_amdgcn_logf(z);  // v_log_f32 = log2
        }

        #pragma unroll
        for (int k = 0; k < 4; ++k) u_cur[k] = u_nxt[k];
    }

    // Combine: out[b] = ln2 * LSE2_i(acc_fwd[i] + acc_bwd[i]).
    if (w == 1) shb[lane] = acc;
    __syncthreads();
    if (w == 0) {
        float v = acc + shb[lane];
        float mx = v;
        #pragma unroll
        for (int k = 32; k >= 1; k >>= 1)
            mx = fmaxf(mx, __shfl_xor(mx, k, 64));
        float ssum = __builtin_amdgcn_exp2f(v - mx);
        #pragma unroll
        for (int k = 32; k >= 1; k >>= 1)
            ssum += __shfl_xor(ssum, k, 64);
        if (lane == 0) out[b] = LN2 * (mx + __builtin_amdgcn_logf(ssum));
    }
}

extern "C" void kernel_launch(void* const* d_in, const int* in_sizes, int n_in,
                              void* d_out, int out_size, void* d_ws, size_t ws_size,
                              hipStream_t stream) {
    const float* unary   = (const float*)d_in[0];
    const int*   lengths = (const int*)d_in[1];
    const float* trans   = (const float*)d_in[2];
    float*       out     = (float*)d_out;

    const int Bb = in_sizes[1];  // 512
    crf_fwd<<<Bb, 128, 0, stream>>>(unary, lengths, trans, out);
}

// Round 9
// 309.427 us; speedup vs baseline: 1.0532x; 1.0532x over previous
//
#include <hip/hip_runtime.h>

// CRF forward: B=512, T=1024, N=64. fwd/bwd split, one wave per chain.
// Round 9 change vs round 8 (single variable):
//  - The 16 q broadcast loads are NAMED and asm-pinned between load and use.
//    R8 falsified the E-reload theory (asm-pinning E changed nothing; E was
//    resident all along: 88 = 64 E + 24 working regs). The real stall: only
//    ~4 of 16 q-f4 reads fit in the 24 working regs, so the ds_read stream
//    issued in ~4 groups, paying ~120cy LDS latency ~4x per step (~480cy of
//    the 846cy/step). Pinning q forces all 16 reads in flight -> one
//    latency hit. (q is freshly loaded each step, so the allocator's
//    reload-is-free heuristic can't be beaten by naming alone - same
//    lesson as R3/R7 - only the asm barrier forces liveness.)

typedef float f4 __attribute__((ext_vector_type(4)));

constexpr int Tt = 1024;
constexpr int Nn = 64;
constexpr int ES = 68;  // f32 row stride: 272 B, 16B-aligned, non-pow2
constexpr float LOG2E = 1.44269504088896340736f;
constexpr float LN2   = 0.69314718055994530942f;

__global__ __launch_bounds__(128, 1) void crf_fwd(
    const float* __restrict__ unary,
    const int*   __restrict__ lengths,
    const float* __restrict__ trans,
    float*       __restrict__ out)
{
    const int b    = blockIdx.x;
    const int tid  = threadIdx.x;
    const int w    = tid >> 6;   // 0 = forward wave, 1 = backward wave
    const int lane = tid & 63;

    __shared__ float Ecol[Nn * ES];   // Ecol[j*ES+i] = exp(trans[i][j])
    __shared__ float Erow[Nn * ES];   // Erow[i*ES+j] = exp(trans[i][j])
    __shared__ f4    shp4[2][Nn / 4]; // per-wave p broadcast (16B-aligned)
    __shared__ float shb[Nn];         // beta at midpoint (combine)

    // One-time staging of E = exp(trans), both orientations.
    #pragma unroll
    for (int c = 0; c < (Nn * Nn) / 128; ++c) {
        int idx = c * 128 + tid;
        int i = idx >> 6, j = idx & 63;
        float e = __expf(trans[idx]);
        Erow[i * ES + j] = e;
        Ecol[j * ES + i] = e;
    }
    __syncthreads();

    // Lane's 64 E values (fwd: column `lane`; bwd: row `lane`).
    const f4* eb = (const f4*)((w == 0) ? &Ecol[lane * ES] : &Erow[lane * ES]);
    f4 E0  = eb[0],  E1  = eb[1],  E2  = eb[2],  E3  = eb[3];
    f4 E4  = eb[4],  E5  = eb[5],  E6  = eb[6],  E7  = eb[7];
    f4 E8  = eb[8],  E9  = eb[9],  E10 = eb[10], E11 = eb[11];
    f4 E12 = eb[12], E13 = eb[13], E14 = eb[14], E15 = eb[15];

    int L = lengths[b];
    L = L < 1 ? 1 : (L > Tt ? Tt : L);
    const int m = (L - 1) >> 1;

    const float* ub = unary + (size_t)b * Tt * Nn;

    const int trips = (w == 0) ? m : (L - 1 - m);
    const int tbase = (w == 0) ? 1 : (L - 1);
    const int dir   = (w == 0) ? 1 : -1;

    // State in base-2 domain: acc = alpha * log2e (or beta * log2e).
    float acc = (w == 0) ? ub[lane] * LOG2E : 0.0f;
    float* myp = (float*)shp4[w];
    const f4* pp = shp4[w];

    // 4-deep u prefetch, premultiplied by log2e (off the dependent chain).
    float u_cur[4];
    {
        int smax = trips > 0 ? trips - 1 : 0;
        #pragma unroll
        for (int k = 0; k < 4; ++k) {
            int sc = k < smax ? k : smax;
            u_cur[k] = ub[(tbase + dir * sc) * Nn + lane] * LOG2E;
        }
    }

    for (int s0 = 0; s0 < trips; s0 += 4) {
        float u_nxt[4];
        #pragma unroll
        for (int k = 0; k < 4; ++k) {
            int sc = s0 + 4 + k;
            if (sc > trips - 1) sc = trips - 1;
            u_nxt[k] = ub[(tbase + dir * sc) * Nn + lane] * LOG2E;
        }

        #pragma unroll
        for (int k = 0; k < 4; ++k) {
            if (s0 + k >= trips) break;  // wave-uniform

            // fwd: p = exp2(acc - s), update = s + u + log2 z
            // bwd: p = exp2(acc + u - s), update = s + log2 z
            float ui = (w != 0) ? u_cur[k] : 0.0f;
            float uo = (w == 0) ? u_cur[k] : 0.0f;

            float tmpv = acc + ui;
            float sf = __uint_as_float(
                (unsigned)__builtin_amdgcn_readfirstlane((int)__float_as_uint(tmpv)));
            float p = __builtin_amdgcn_exp2f(tmpv - sf);

            myp[lane] = p;  // intra-wave ds_write; LDS pipe in-order

            // All 16 broadcast reads issued together, completed ONCE:
            // the asm barrier makes them simultaneously live, so the
            // allocator cannot serialize them into reload groups.
            f4 q0  = pp[0],  q1  = pp[1],  q2  = pp[2],  q3  = pp[3];
            f4 q4  = pp[4],  q5  = pp[5],  q6  = pp[6],  q7  = pp[7];
            f4 q8  = pp[8],  q9  = pp[9],  q10 = pp[10], q11 = pp[11];
            f4 q12 = pp[12], q13 = pp[13], q14 = pp[14], q15 = pp[15];
            asm volatile("" : "+v"(q0),  "+v"(q1),  "+v"(q2),  "+v"(q3),
                              "+v"(q4),  "+v"(q5),  "+v"(q6),  "+v"(q7),
                              "+v"(q8),  "+v"(q9),  "+v"(q10), "+v"(q11),
                              "+v"(q12), "+v"(q13), "+v"(q14), "+v"(q15));

            f4 A0 = {0.f, 0.f, 0.f, 0.f};
            f4 A1 = {0.f, 0.f, 0.f, 0.f};
            f4 A2 = {0.f, 0.f, 0.f, 0.f};
            f4 A3 = {0.f, 0.f, 0.f, 0.f};
            A0 = q0  * E0  + A0;  A1 = q1  * E1  + A1;
            A2 = q2  * E2  + A2;  A3 = q3  * E3  + A3;
            A0 = q4  * E4  + A0;  A1 = q5  * E5  + A1;
            A2 = q6  * E6  + A2;  A3 = q7  * E7  + A3;
            A0 = q8  * E8  + A0;  A1 = q9  * E9  + A1;
            A2 = q10 * E10 + A2;  A3 = q11 * E11 + A3;
            A0 = q12 * E12 + A0;  A1 = q13 * E13 + A1;
            A2 = q14 * E14 + A2;  A3 = q15 * E15 + A3;
            f4 S = (A0 + A1) + (A2 + A3);
            float z = (S.x + S.y) + (S.z + S.w);

            acc = sf + uo + __builtin_amdgcn_logf(z);  // v_log_f32 = log2
        }

        #pragma unroll
        for (int k = 0; k < 4; ++k) u_cur[k] = u_nxt[k];
    }

    // Combine: out[b] = ln2 * LSE2_i(acc_fwd[i] + acc_bwd[i]).
    if (w == 1) shb[lane] = acc;
    __syncthreads();
    if (w == 0) {
        float v = acc + shb[lane];
        float mx = v;
        #pragma unroll
        for (int k = 32; k >= 1; k >>= 1)
            mx = fmaxf(mx, __shfl_xor(mx, k, 64));
        float ssum = __builtin_amdgcn_exp2f(v - mx);
        #pragma unroll
        for (int k = 32; k >= 1; k >>= 1)
            ssum += __shfl_xor(ssum, k, 64);
        if (lane == 0) out[b] = LN2 * (mx + __builtin_amdgcn_logf(ssum));
    }
}

extern "C" void kernel_launch(void* const* d_in, const int* in_sizes, int n_in,
                              void* d_out, int out_size, void* d_ws, size_t ws_size,
                              hipStream_t stream) {
    const float* unary   = (const float*)d_in[0];
    const int*   lengths = (const int*)d_in[1];
    const float* trans   = (const float*)d_in[2];
    float*       out     = (float*)d_out;

    const int Bb = in_sizes[1];  // 512
    crf_fwd<<<Bb, 128, 0, stream>>>(unary, lengths, trans, out);
}

// Round 10
// 296.874 us; speedup vs baseline: 1.0978x; 1.0423x over previous
//
#include <hip/hip_runtime.h>

// CRF forward: B=512, T=1024, N=64. fwd/bwd split, one wave per chain.
// Round 10: EXP-DOMAIN recurrence. The log-domain form pays exp+log+
// readfirstlane on the dependent chain every step only to re-normalize.
// Drift is bounded (~14 bits/step worst case), so instead:
//   a'_j = (sum_i a_i E_ij) * w_j,  w_j = exp(u_t[j]) precomputed OFF-chain
// with an exact exponent-only rescale every 4 steps:
//   e = exponent(lane0(a)); off += e; a *= 2^-e   (one v_mul, no rounding)
// Chain per step: ds_write -> 16 pinned ds_read_b128 -> pk_fma -> v_mul.
// No transcendentals anywhere in the loop. Output:
//   out = ln2 * (off_f + off_b + log2(sum_i a_i b_i)).

typedef float f4 __attribute__((ext_vector_type(4)));

constexpr int Tt = 1024;
constexpr int Nn = 64;
constexpr int ES = 68;  // f32 row stride: 272 B, 16B-aligned, non-pow2
constexpr float LN2 = 0.69314718055994530942f;

__global__ __launch_bounds__(128, 1) void crf_fwd(
    const float* __restrict__ unary,
    const int*   __restrict__ lengths,
    const float* __restrict__ trans,
    float*       __restrict__ out)
{
    const int b    = blockIdx.x;
    const int tid  = threadIdx.x;
    const int w    = tid >> 6;   // 0 = forward wave, 1 = backward wave
    const int lane = tid & 63;

    __shared__ float Ecol[Nn * ES];   // Ecol[j*ES+i] = exp(trans[i][j])
    __shared__ float Erow[Nn * ES];   // Erow[i*ES+j] = exp(trans[i][j])
    __shared__ f4    shp4[2][Nn / 4]; // per-wave a broadcast (16B-aligned)
    __shared__ float shb[Nn];         // beta at midpoint (combine)
    __shared__ int   sh_off_b;        // bwd exponent offset

    // One-time staging of E = exp(trans), both orientations.
    #pragma unroll
    for (int c = 0; c < (Nn * Nn) / 128; ++c) {
        int idx = c * 128 + tid;
        int i = idx >> 6, j = idx & 63;
        float e = __expf(trans[idx]);
        Erow[i * ES + j] = e;
        Ecol[j * ES + i] = e;
    }
    __syncthreads();

    // Lane's 64 E values (fwd: column `lane`; bwd: row `lane`).
    const f4* eb = (const f4*)((w == 0) ? &Ecol[lane * ES] : &Erow[lane * ES]);
    f4 E0  = eb[0],  E1  = eb[1],  E2  = eb[2],  E3  = eb[3];
    f4 E4  = eb[4],  E5  = eb[5],  E6  = eb[6],  E7  = eb[7];
    f4 E8  = eb[8],  E9  = eb[9],  E10 = eb[10], E11 = eb[11];
    f4 E12 = eb[12], E13 = eb[13], E14 = eb[14], E15 = eb[15];

    int L = lengths[b];
    L = L < 1 ? 1 : (L > Tt ? Tt : L);
    const int m = (L - 1) >> 1;

    const float* ub = unary + (size_t)b * Tt * Nn;

    const int trips = (w == 0) ? m : (L - 1 - m);
    const int tbase = (w == 0) ? 1 : (L - 1);
    const int dir   = (w == 0) ? 1 : -1;

    // Exp-domain state + exponent offset.
    float acc = (w == 0) ? __expf(ub[lane]) : 1.0f;
    int   off = 0;
    float* myp = (float*)shp4[w];
    const f4* pp = shp4[w];

    // 4-deep prefetch of w_t = exp(u_t) (loads + exps are all off-chain).
    float w_cur[4];
    {
        int smax = trips > 0 ? trips - 1 : 0;
        #pragma unroll
        for (int k = 0; k < 4; ++k) {
            int sc = k < smax ? k : smax;
            w_cur[k] = __expf(ub[(tbase + dir * sc) * Nn + lane]);
        }
    }

    for (int s0 = 0; s0 < trips; s0 += 4) {
        float w_nxt[4];
        #pragma unroll
        for (int k = 0; k < 4; ++k) {
            int sc = s0 + 4 + k;
            if (sc > trips - 1) sc = trips - 1;
            w_nxt[k] = __expf(ub[(tbase + dir * sc) * Nn + lane]);
        }

        #pragma unroll
        for (int k = 0; k < 4; ++k) {
            if (s0 + k >= trips) break;  // wave-uniform

            // fwd: a' = (E^T a) * w   (w on output)
            // bwd: a' = E (w * a)     (w on input)
            float win  = (w != 0) ? w_cur[k] : 1.0f;
            float wout = (w == 0) ? w_cur[k] : 1.0f;

            myp[lane] = acc * win;  // same-wave DS ops are in-order

            f4 q0  = pp[0],  q1  = pp[1],  q2  = pp[2],  q3  = pp[3];
            f4 q4  = pp[4],  q5  = pp[5],  q6  = pp[6],  q7  = pp[7];
            f4 q8  = pp[8],  q9  = pp[9],  q10 = pp[10], q11 = pp[11];
            f4 q12 = pp[12], q13 = pp[13], q14 = pp[14], q15 = pp[15];
            asm volatile("" : "+v"(q0),  "+v"(q1),  "+v"(q2),  "+v"(q3),
                              "+v"(q4),  "+v"(q5),  "+v"(q6),  "+v"(q7),
                              "+v"(q8),  "+v"(q9),  "+v"(q10), "+v"(q11),
                              "+v"(q12), "+v"(q13), "+v"(q14), "+v"(q15));

            f4 A0 = {0.f, 0.f, 0.f, 0.f};
            f4 A1 = {0.f, 0.f, 0.f, 0.f};
            f4 A2 = {0.f, 0.f, 0.f, 0.f};
            f4 A3 = {0.f, 0.f, 0.f, 0.f};
            A0 = q0  * E0  + A0;  A1 = q1  * E1  + A1;
            A2 = q2  * E2  + A2;  A3 = q3  * E3  + A3;
            A0 = q4  * E4  + A0;  A1 = q5  * E5  + A1;
            A2 = q6  * E6  + A2;  A3 = q7  * E7  + A3;
            A0 = q8  * E8  + A0;  A1 = q9  * E9  + A1;
            A2 = q10 * E10 + A2;  A3 = q11 * E11 + A3;
            A0 = q12 * E12 + A0;  A1 = q13 * E13 + A1;
            A2 = q14 * E14 + A2;  A3 = q15 * E15 + A3;
            f4 S = (A0 + A1) + (A2 + A3);
            float z = (S.x + S.y) + (S.z + S.w);

            acc = z * wout;
        }

        // Exact exponent-only rescale (once per 4 steps; keeps fp32 in range:
        // worst drift 4 steps * ~14 bits + ~10 bits lane spread << 126).
        {
            unsigned s0b = (unsigned)__builtin_amdgcn_readfirstlane(
                (int)__float_as_uint(acc));
            int e = (int)((s0b >> 23) & 0xFF) - 127;
            off += e;
            acc *= __uint_as_float((unsigned)(127 - e) << 23);
        }

        #pragma unroll
        for (int k = 0; k < 4; ++k) w_cur[k] = w_nxt[k];
    }

    // Combine: out[b] = ln2 * (off_f + off_b + log2(sum_i a_i * b_i)).
    if (w == 1) {
        shb[lane] = acc;
        if (lane == 0) sh_off_b = off;
    }
    __syncthreads();
    if (w == 0) {
        float v = acc * shb[lane];
        float ssum = v;
        #pragma unroll
        for (int k = 32; k >= 1; k >>= 1)
            ssum += __shfl_xor(ssum, k, 64);
        if (lane == 0) {
            float l2 = __builtin_amdgcn_logf(ssum);  // v_log_f32 = log2
            out[b] = LN2 * ((float)(off + sh_off_b) + l2);
        }
    }
}

extern "C" void kernel_launch(void* const* d_in, const int* in_sizes, int n_in,
                              void* d_out, int out_size, void* d_ws, size_t ws_size,
                              hipStream_t stream) {
    const float* unary   = (const float*)d_in[0];
    const int*   lengths = (const int*)d_in[1];
    const float* trans   = (const float*)d_in[2];
    float*       out     = (float*)d_out;

    const int Bb = in_sizes[1];  // 512
    crf_fwd<<<Bb, 128, 0, stream>>>(unary, lengths, trans, out);
}